// Round 20
// baseline (70.536 us; speedup 1.0000x reference)
//
#include <hip/hip_runtime.h>

#define NSTATE 128
#define NM1    127
#define UDIM   4
#define NCOEF  35
#define CSTR   37

typedef float v4f  __attribute__((ext_vector_type(4)));
typedef _Float16 h2 __attribute__((ext_vector_type(2)));

// R20: R17 (best, 57.2us) + lse SPLIT-OFF via R9-validated Taylor polynomial.
//  k_build_wh: fp16 de-interleaved W table (128KB) -> ws[0,128K)
//  k_coeff   : per-state 3rd-order moments (R9 verbatim, absmax-validated)
//              -> ws[128K, 128K+18.9K)
//  k_lse     : thread-per-row, coeffs in LDS, ~45 FMA + log, NO shuffles,
//              writes fp16 lse (1MB) -> ws[150016, +2T)   (lse ~ +-0.3, ulp 2e-4)
//  k_out     : R17 hot kernel MINUS 4 exp + 1 log + 5 shuffles per iter ->
//              per pair-iter: 2 ds_read_b128 (w), uniform u/lp/lse loads,
//              8 fdot2, 4 subs, 1KB nt store. Nearly pure write stream.
// Rationale: R19 showed the DS pipe is the loaded resource (adding lp LDS
// reads cost 5us); R16 showed more ILP is null. Removing DS+trans ops is the
// one untested direction. NT stores required (R15: plain +49%); grid-dense
// mapping required (R17: +8us); no per-iter barrier (R18: +10%).

__device__ __forceinline__ h2 as_h2(unsigned v) {
    union { unsigned u; h2 h; } c; c.u = v; return c.h;
}

__device__ __forceinline__ float dot2x2(unsigned wlo, unsigned whi, h2 u01, h2 u23) {
#if __has_builtin(__builtin_amdgcn_fdot2)
    return __builtin_amdgcn_fdot2(as_h2(wlo), u01,
           __builtin_amdgcn_fdot2(as_h2(whi), u23, 0.0f, false), false);
#else
    h2 a = as_h2(wlo), b = as_h2(whi);
    return (float)a[0] * (float)u01[0] + (float)a[1] * (float)u01[1]
         + (float)b[0] * (float)u23[0] + (float)b[1] * (float)u23[1];
#endif
}

__device__ __forceinline__ float dot4(const float4 a, const float4 b) {
    return fmaf(a.x, b.x, fmaf(a.y, b.y, fmaf(a.z, b.z, a.w * b.w)));
}

// ---------------- pre-pass 1: fp16 W table ----------------
__global__ __launch_bounds__(128) void k_build_wh(
    const float* __restrict__ W, char* __restrict__ Wh)
{
    const int s = blockIdx.x;     // 0..127
    const int j = threadIdx.x;    // 0..127
    float4 w = make_float4(0.0f, 0.0f, 0.0f, 0.0f);
    if (j != s) {
        const int k = j - (j > s);
        w = *reinterpret_cast<const float4*>(W + ((size_t)s * NM1 + k) * UDIM);
    }
    h2 a; a[0] = (_Float16)w.x; a[1] = (_Float16)w.y;
    h2 b; b[0] = (_Float16)w.z; b[1] = (_Float16)w.w;
    const size_t off = (size_t)s * 1024 + (size_t)((j >> 1) & 1) * 512
                     + (size_t)(j >> 2) * 16 + (size_t)(j & 1) * 8;
    *reinterpret_cast<h2*>(Wh + off)     = a;
    *reinterpret_cast<h2*>(Wh + off + 4) = b;
}

// ---------------- pre-pass 2: per-state Taylor moments (R9 verbatim) ----------------
__global__ __launch_bounds__(NSTATE) void k_coeff(
    const float* __restrict__ logP0, const float* __restrict__ W,
    float* __restrict__ coeff)
{
    __shared__ float red[NCOEF][NSTATE + 1];
    const int s = blockIdx.x, j = threadIdx.x;

    float wa[4] = {0.0f, 0.0f, 0.0f, 0.0f};
    if (j != s) {
        const int k = j - (j > s);
        const float4 w = *reinterpret_cast<const float4*>(W + ((size_t)s * NM1 + k) * UDIM);
        wa[0] = w.x; wa[1] = w.y; wa[2] = w.z; wa[3] = w.w;
    }
    const float P = __expf(logP0[s * NSTATE + j]);

    red[0][j] = P;
    #pragma unroll
    for (int a = 0; a < 4; ++a) red[1 + a][j] = P * wa[a];

    constexpr int PA_[10] = {0,0,0,0,1,1,1,2,2,3};
    constexpr int PB_[10] = {0,1,2,3,1,2,3,2,3,3};
    #pragma unroll
    for (int p = 0; p < 10; ++p) {
        const float mlt = (PA_[p] == PB_[p]) ? 0.5f : 1.0f;
        red[5 + p][j] = P * wa[PA_[p]] * wa[PB_[p]] * mlt;
    }
    constexpr int TA_[20] = {0,0,0,0,0,0,0,0,0,0,1,1,1,1,1,1,2,2,2,3};
    constexpr int TB_[20] = {0,0,0,0,1,1,1,2,2,3,1,1,1,2,2,3,2,2,3,3};
    constexpr int TC_[20] = {0,1,2,3,1,2,3,2,3,3,1,2,3,2,3,3,2,3,3,3};
    #pragma unroll
    for (int q = 0; q < 20; ++q) {
        const int a = TA_[q], b = TB_[q], c = TC_[q];
        const float mlt = (a == b && b == c) ? (1.0f / 6.0f)
                        : ((a == b || b == c) ? 0.5f : 1.0f);
        red[15 + q][j] = P * wa[a] * wa[b] * wa[c] * mlt;
    }
    __syncthreads();

    if (j < NCOEF) {
        float acc = 0.0f;
        #pragma unroll 4
        for (int i = 0; i < NSTATE; ++i) acc += red[j][i];
        coeff[s * CSTR + j] = acc;
    }
}

// ---------------- pass 3: thread-per-row polynomial lse (fp16 out) ----------------
__global__ __launch_bounds__(256) void k_lse(
    const int* __restrict__ x, const float* __restrict__ u,
    const float* __restrict__ coeff, _Float16* __restrict__ lse, int T)
{
    __shared__ float C[NSTATE * CSTR];
    for (int i = threadIdx.x; i < NSTATE * CSTR; i += blockDim.x) C[i] = coeff[i];
    __syncthreads();

    const int stride = gridDim.x * blockDim.x;
    for (int t = blockIdx.x * blockDim.x + threadIdx.x; t < T; t += stride) {
        const int s = x[t];
        const float4 uv = *reinterpret_cast<const float4*>(u + (size_t)t * UDIM);
        const float ua[4] = {uv.x, uv.y, uv.z, uv.w};
        const float* Cb = &C[s * CSTR];

        float z = Cb[0];
        #pragma unroll
        for (int a = 0; a < 4; ++a) z = fmaf(ua[a], Cb[1 + a], z);

        constexpr int PA_[10] = {0,0,0,0,1,1,1,2,2,3};
        constexpr int PB_[10] = {0,1,2,3,1,2,3,2,3,3};
        float uu[10];
        #pragma unroll
        for (int p = 0; p < 10; ++p) uu[p] = ua[PA_[p]] * ua[PB_[p]];
        #pragma unroll
        for (int p = 0; p < 10; ++p) z = fmaf(uu[p], Cb[5 + p], z);

        constexpr int TQ_[20] = {0,1,2,3,4,5,6,7,8,9,4,5,6,7,8,9,7,8,9,9};
        constexpr int TC_[20] = {0,1,2,3,1,2,3,2,3,3,1,2,3,2,3,3,2,3,3,3};
        #pragma unroll
        for (int q = 0; q < 20; ++q)
            z = fmaf(uu[TQ_[q]] * ua[TC_[q]], Cb[15 + q], z);

        lse[t] = (_Float16)__logf(z);
    }
}

// ---------------- pass 4: hot output kernel (R17 minus softmax) ----------------
__global__ __launch_bounds__(1024) void k_out(
    const int*      __restrict__ x_curr,
    const float*    __restrict__ u_curr,
    const float*    __restrict__ logP0,
    const uint4*    __restrict__ Wh,
    const _Float16* __restrict__ lse,
    float*          __restrict__ out,
    int T)
{
    __shared__ uint4 wt[8192];    // 128 KB

    const int tid = threadIdx.x;
    #pragma unroll
    for (int i = 0; i < 8; ++i)
        wt[tid + i * 1024] = Wh[tid + i * 1024];
    __syncthreads();

    const int lane = tid & 63;
    const int wv   = tid >> 6;      // 0..15
    const int h    = lane >> 5;     // 0 = row 2p, 1 = row 2p+1
    const int lh   = lane & 31;
    const int j0   = 4 * lh;

    const int npairs = (T + 1) >> 1;
    const int nw     = gridDim.x * 16;          // total waves (4096)
    const int pstart = blockIdx.x * 16 + wv;    // dense front

    for (int p = pstart; p < npairs; p += nw) {
        const int r0 = 2 * p;
        const int r1 = (r0 + 1 < T) ? (r0 + 1) : r0;   // odd-T clamp (benign dup)

        int s0 = x_curr[r0], s1 = x_curr[r1];
        s0 = __builtin_amdgcn_readfirstlane(s0);
        s1 = __builtin_amdgcn_readfirstlane(s1);
        const int s = h ? s1 : s0;
        const int r = h ? r1 : r0;

        const float4 uv = *reinterpret_cast<const float4*>(u_curr + (size_t)r * UDIM);
        h2 u01; u01[0] = (_Float16)uv.x; u01[1] = (_Float16)uv.y;
        h2 u23; u23[0] = (_Float16)uv.z; u23[1] = (_Float16)uv.w;

        const uint4 w0 = wt[s * 64 + lh];
        const uint4 w1 = wt[s * 64 + 32 + lh];

        const float4 lp = *reinterpret_cast<const float4*>(logP0 + (size_t)s * NSTATE + j0);

        const float l = (float)lse[r];   // uniform per half: broadcast 2B load

        const float v0 = lp.x + dot2x2(w0.x, w0.y, u01, u23) - l;
        const float v1 = lp.y + dot2x2(w0.z, w0.w, u01, u23) - l;
        const float v2 = lp.z + dot2x2(w1.x, w1.y, u01, u23) - l;
        const float v3 = lp.w + dot2x2(w1.z, w1.w, u01, u23) - l;

        v4f ov;
        ov[0] = v0; ov[1] = v1; ov[2] = v2; ov[3] = v3;
        __builtin_nontemporal_store(
            ov, reinterpret_cast<v4f*>(out + (size_t)r * NSTATE + j0));
    }
}

// ---------------- R17 hot kernel (fallback tier 2: ws fits table only) ----------------
__global__ __launch_bounds__(1024) void k_seq(
    const int*   __restrict__ x_curr,
    const float* __restrict__ u_curr,
    const float* __restrict__ logP0,
    const uint4* __restrict__ Wh,
    float*       __restrict__ out,
    int T)
{
    __shared__ uint4 wt[8192];

    const int tid = threadIdx.x;
    #pragma unroll
    for (int i = 0; i < 8; ++i)
        wt[tid + i * 1024] = Wh[tid + i * 1024];
    __syncthreads();

    const int lane = tid & 63;
    const int wv   = tid >> 6;
    const int h    = lane >> 5;
    const int lh   = lane & 31;
    const int j0   = 4 * lh;

    const int npairs = (T + 1) >> 1;
    const int nw     = gridDim.x * 16;
    const int pstart = blockIdx.x * 16 + wv;

    for (int p = pstart; p < npairs; p += nw) {
        const int r0 = 2 * p;
        const int r1 = (r0 + 1 < T) ? (r0 + 1) : r0;

        int s0 = x_curr[r0], s1 = x_curr[r1];
        s0 = __builtin_amdgcn_readfirstlane(s0);
        s1 = __builtin_amdgcn_readfirstlane(s1);
        const int s = h ? s1 : s0;
        const int r = h ? r1 : r0;

        const float4 uv = *reinterpret_cast<const float4*>(u_curr + (size_t)r * UDIM);
        h2 u01; u01[0] = (_Float16)uv.x; u01[1] = (_Float16)uv.y;
        h2 u23; u23[0] = (_Float16)uv.z; u23[1] = (_Float16)uv.w;

        const uint4 w0 = wt[s * 64 + lh];
        const uint4 w1 = wt[s * 64 + 32 + lh];

        const float4 lp = *reinterpret_cast<const float4*>(logP0 + (size_t)s * NSTATE + j0);

        const float v0 = lp.x + dot2x2(w0.x, w0.y, u01, u23);
        const float v1 = lp.y + dot2x2(w0.z, w0.w, u01, u23);
        const float v2 = lp.z + dot2x2(w1.x, w1.y, u01, u23);
        const float v3 = lp.w + dot2x2(w1.z, w1.w, u01, u23);

        float e = (__expf(v0) + __expf(v1)) + (__expf(v2) + __expf(v3));
        #pragma unroll
        for (int o = 16; o >= 1; o >>= 1)
            e += __shfl_xor(e, o, 64);
        const float l = __logf(e);

        v4f ov;
        ov[0] = v0 - l; ov[1] = v1 - l; ov[2] = v2 - l; ov[3] = v3 - l;
        __builtin_nontemporal_store(
            ov, reinterpret_cast<v4f*>(out + (size_t)r * NSTATE + j0));
    }
}

// ---------------- fallback tier 3: direct kernel, no ws ----------------
__global__ __launch_bounds__(256) void k_fallback(
    const int* __restrict__ x_curr, const float* __restrict__ u_curr,
    const float* __restrict__ logP0, const float* __restrict__ W,
    float* __restrict__ out, int T)
{
    const int lane    = threadIdx.x & 63;
    const int wave_id = (blockIdx.x * blockDim.x + threadIdx.x) >> 6;
    const int nwaves  = (gridDim.x * blockDim.x) >> 6;
    const int j0 = 2 * lane, j1 = j0 + 1;
    for (int t = wave_id; t < T; t += nwaves) {
        int s = x_curr[t];
        s = __builtin_amdgcn_readfirstlane(s);
        const float4 uv = *reinterpret_cast<const float4*>(u_curr + (size_t)t * UDIM);
        float st0 = 0.0f, st1 = 0.0f;
        if (j0 != s) {
            const int k = j0 - (j0 > s);
            const float4 w = *reinterpret_cast<const float4*>(W + ((size_t)s * NM1 + k) * UDIM);
            st0 = dot4(uv, w);
        }
        if (j1 != s) {
            const int k = j1 - (j1 > s);
            const float4 w = *reinterpret_cast<const float4*>(W + ((size_t)s * NM1 + k) * UDIM);
            st1 = dot4(uv, w);
        }
        const float2 lp = *reinterpret_cast<const float2*>(logP0 + (size_t)s * NSTATE + j0);
        const float v0 = lp.x + st0, v1 = lp.y + st1;
        float e = __expf(v0) + __expf(v1);
        #pragma unroll
        for (int o = 32; o >= 1; o >>= 1)
            e += __shfl_xor(e, o, 64);
        const float l = __logf(e);
        float2 o2; o2.x = v0 - l; o2.y = v1 - l;
        *reinterpret_cast<float2*>(out + (size_t)t * NSTATE + j0) = o2;
    }
}

extern "C" void kernel_launch(void* const* d_in, const int* in_sizes, int n_in,
                              void* d_out, int out_size, void* d_ws, size_t ws_size,
                              hipStream_t stream) {
    const int*   x_curr = (const int*)  d_in[0];
    const float* u_curr = (const float*)d_in[1];
    const float* logP0  = (const float*)d_in[2];
    const float* W      = (const float*)d_in[3];
    float*       out    = (float*)d_out;

    const int T = in_sizes[0];

    // ws layout: [0,128K) W table | [128K, +18944) coeff | [150016, +2T) lse fp16
    const size_t need_tab   = 131072;
    const size_t off_coeff  = 131072;
    const size_t off_lse    = 150016;
    const size_t need_split = off_lse + (size_t)2 * T;

    if (ws_size < need_tab || T < 2) {
        hipLaunchKernelGGL(k_fallback, dim3(2048), dim3(256), 0, stream,
                           x_curr, u_curr, logP0, W, out, T);
        return;
    }

    hipLaunchKernelGGL(k_build_wh, dim3(NSTATE), dim3(NSTATE), 0, stream,
                       W, (char*)d_ws);

    if (ws_size < need_split) {
        hipLaunchKernelGGL(k_seq, dim3(256), dim3(1024), 0, stream,
                           x_curr, u_curr, logP0, (const uint4*)d_ws, out, T);
        return;
    }

    float*     coeff = (float*)((char*)d_ws + off_coeff);
    _Float16*  lseh  = (_Float16*)((char*)d_ws + off_lse);

    int nblk_lse = (T + 255) / 256;
    if (nblk_lse > 2048) nblk_lse = 2048;

    hipLaunchKernelGGL(k_coeff, dim3(NSTATE), dim3(NSTATE), 0, stream,
                       logP0, W, coeff);
    hipLaunchKernelGGL(k_lse, dim3(nblk_lse), dim3(256), 0, stream,
                       x_curr, u_curr, coeff, lseh, T);
    hipLaunchKernelGGL(k_out, dim3(256), dim3(1024), 0, stream,
                       x_curr, u_curr, logP0, (const uint4*)d_ws, lseh, out, T);
}